// Round 1
// baseline (219.502 us; speedup 1.0000x reference)
//
#include <hip/hip_runtime.h>
#include <hip/hip_bf16.h>

// Problem constants (B=8192, D=128 from reference setup_inputs)
constexpr int Bh = 8192;
constexpr int Nn = 16384;   // 2*B
constexpr int Dd = 128;
constexpr float EPS = 1e-8f;
constexpr float LN2 = 0.69314718056f;

constexpr int K_TILES = 4;          // tiles per block
constexpr int N_TILES = 8256;       // 128x128 upper-tri tiles (incl diag): 128*129/2
constexpr int N_BLOCKS = N_TILES / K_TILES;   // 2064, exact

typedef short bf16x8 __attribute__((ext_vector_type(8)));
typedef float f32x4 __attribute__((ext_vector_type(4)));

// ---- Kernel 1: fp32 -> bf16, scaled by sqrt(2*log2e) so MFMA dot == sim/tau*log2e ----
__global__ __launch_bounds__(256) void convert_kernel(const float4* __restrict__ za,
                                                      const float4* __restrict__ zb,
                                                      ushort* __restrict__ z,
                                                      float* __restrict__ rowsum) {
    const int t = blockIdx.x * 256 + threadIdx.x;        // 0 .. 524287
    constexpr int Q = (Bh * Dd) / 4;                     // 262144 float4 per input
    const float SCL = 1.69864363f;                       // sqrt(2 * 1.4426950409)
    float4 v = (t < Q) ? za[t] : zb[t - Q];
    union { ushort4 u4; __hip_bfloat16 h[4]; } cv;
    cv.h[0] = __float2bfloat16(v.x * SCL);
    cv.h[1] = __float2bfloat16(v.y * SCL);
    cv.h[2] = __float2bfloat16(v.z * SCL);
    cv.h[3] = __float2bfloat16(v.w * SCL);
    ((ushort4*)z)[t] = cv.u4;
    if (t < Nn) rowsum[t] = 0.f;
}

// tile index g -> row tile t (128-row granularity): largest t with cum(t)=t*(257-t)/2 <= g
__device__ __forceinline__ int row_tile_of(int g) {
    int t = (int)((257.0f - sqrtf(66049.0f - 8.0f * (float)g)) * 0.5f);
    t = t < 0 ? 0 : (t > 127 ? 127 : t);
    while (t * (257 - t) / 2 > g) --t;
    while ((t + 1) * (256 - t) / 2 <= g) ++t;
    return t;
}

// row-credit flush: reduce rs over the 16 col-lanes, one atomic per row (log2 domain)
__device__ __forceinline__ void flush_rs(float* __restrict__ rowsum, int rowW,
                                         float (&rs)[2][4], int q, int c) {
#pragma unroll
    for (int s = 0; s < 2; ++s)
#pragma unroll
        for (int r = 0; r < 4; ++r) {
            float v = rs[s][r];
            v += __shfl_xor(v, 1);
            v += __shfl_xor(v, 2);
            v += __shfl_xor(v, 4);
            v += __shfl_xor(v, 8);
            if (c == 0) atomicAdd(&rowsum[rowW + s * 16 + q * 4 + r], v);
            rs[s][r] = 0.f;
        }
}

// ---- Kernel 2: symmetric upper-triangle at 128x128 granularity, NO LDS / NO BARRIERS.
// R6 change vs the 209-us kernel: waves own 32 rows (not 64) so per-wave A-state
// halves (afrag 64->32 VGPR). Target <=128 VGPR -> 4 waves/SIMD (was 160 -> 3),
// and grid grows 1040 -> 2064 equal-cost blocks (~2 clean occupancy rounds,
// no intra-block diagonal skip divergence). The kernel was latency-bound:
// MfmaUtil 8.9% == the exact MFMA floor, VALUBusy 32%, everything else idle.
// NOTE: plain __launch_bounds__(256) — a min-waves arg clamps VGPRs and spills.
__global__ __launch_bounds__(256) void main_kernel(const ushort* __restrict__ z,
                                                   float* __restrict__ rowsum,
                                                   float* __restrict__ pospair) {
    const int tid = threadIdx.x;
    const int wave = tid >> 6;
    const int lane = tid & 63;
    const int q = lane >> 4;        // quad: 0..3
    const int c = lane & 15;        // 0..15
    const int g0 = blockIdx.x * K_TILES;

    bf16x8 afrag[2][4];
    float rs[2][4];
    float csum[8];
    int cur_tr = -1;
    int rowW = 0;

#pragma unroll
    for (int s = 0; s < 2; ++s)
#pragma unroll
        for (int r = 0; r < 4; ++r) rs[s][r] = 0.f;
#pragma unroll
    for (int st = 0; st < 8; ++st) csum[st] = 0.f;

    for (int j = 0; j < K_TILES; ++j) {
        const int g = g0 + j;
        const int tr = row_tile_of(g);
        const int ct = tr + (g - tr * (257 - tr) / 2);
        const int C0 = ct << 7;

        if (tr != cur_tr) {
            if (cur_tr >= 0) flush_rs(rowsum, rowW, rs, q, c);
            cur_tr = tr;
            rowW = (tr << 7) + wave * 32;      // this wave's 32-row base
#pragma unroll
            for (int s = 0; s < 2; ++s) {
                const ushort* ap = z + (size_t)(rowW + s * 16 + c) * Dd;
#pragma unroll
                for (int kt = 0; kt < 4; ++kt)
                    afrag[s][kt] = *(const bf16x8*)(ap + kt * 32 + q * 8);
            }
        }
        const bool diag = (ct == tr);

        // per-lane B base: col = C0 + c, k-offset q*8; bfrag(st,kt) at +st*2048 + kt*32
        const ushort* bp = z + ((size_t)(C0 + c) << 7) + (q << 3);

        bf16x8 bcur[4], bnxt[4];
#pragma unroll
        for (int kt = 0; kt < 4; ++kt) bcur[kt] = *(const bf16x8*)(bp + kt * 32);

#pragma unroll
        for (int st = 0; st < 8; ++st) {
            if (st < 7) {     // prefetch next st's B while this st computes
#pragma unroll
                for (int kt = 0; kt < 4; ++kt)
                    bnxt[kt] = *(const bf16x8*)(bp + (st + 1) * 2048 + kt * 32);
            }
            f32x4 acc[2] = {{0.f,0.f,0.f,0.f},{0.f,0.f,0.f,0.f}};
#pragma unroll
            for (int kt = 0; kt < 4; ++kt) {
#pragma unroll
                for (int s = 0; s < 2; ++s)
                    acc[s] = __builtin_amdgcn_mfma_f32_16x16x32_bf16(afrag[s][kt], bcur[kt], acc[s], 0, 0, 0);
            }
            const int gc0 = C0 + st * 16;
#pragma unroll
            for (int s = 0; s < 2; ++s) {
                const int R = rowW + s * 16;
                float sp[4];
#pragma unroll
                for (int r = 0; r < 4; ++r) {
                    float u = acc[s][r];
                    // softplus in log2 domain: max(u,0) + log2(1 + 2^-|u|)
                    float e = __builtin_amdgcn_exp2f(-fabsf(u));
                    sp[r] = fmaxf(u, 0.f) + __builtin_amdgcn_logf(1.f + e);
                }
                if (diag && gc0 == R) {               // zero self-similarity
#pragma unroll
                    for (int r = 0; r < 4; ++r)
                        if (c == q * 4 + r) sp[r] = 0.f;
                }
                if (gc0 == (R ^ Bh)) {                // positive-pair subtile (rows<8192)
#pragma unroll
                    for (int r = 0; r < 4; ++r)
                        if (c == q * 4 + r) pospair[R + q * 4 + r] = sp[r];
                }
#pragma unroll
                for (int r = 0; r < 4; ++r) rs[s][r] += sp[r];
                if (!diag) csum[st] += (sp[0] + sp[1]) + (sp[2] + sp[3]);
            }
#pragma unroll
            for (int kt = 0; kt < 4; ++kt) bcur[kt] = bnxt[kt];
        }
        if (!diag) {   // col credit: reduce over q (rows), one atomic per col
#pragma unroll
            for (int st = 0; st < 8; ++st) {
                float v = csum[st];
                v += __shfl_xor(v, 16);
                v += __shfl_xor(v, 32);
                if (lane < 16) atomicAdd(&rowsum[C0 + st * 16 + c], v);
                csum[st] = 0.f;
            }
        }
    }
    if (cur_tr >= 0) flush_rs(rowsum, rowW, rs, q, c);
}

// ---- Kernel 3: final loss (log2-domain sums back via ln2), 1024 threads ----
__global__ __launch_bounds__(1024) void finalize_kernel(const float* __restrict__ rowsum,
                                                        const float* __restrict__ pospair,
                                                        float* __restrict__ out) {
    __shared__ float red[16];
    float acc = 0.f;
    for (int i = threadIdx.x; i < Nn; i += 1024) {
        float denom = fmaxf(LN2 * rowsum[i], EPS);
        float sp = fmaxf(LN2 * pospair[i & (Bh - 1)], EPS);   // pospair[i]==pospair[i^B]
        acc += __logf(sp) - __logf(denom);
    }
#pragma unroll
    for (int m = 1; m < 64; m <<= 1) acc += __shfl_xor(acc, m);
    if ((threadIdx.x & 63) == 0) red[threadIdx.x >> 6] = acc;
    __syncthreads();
    if (threadIdx.x < 16) {
        float v = red[threadIdx.x];
        v += __shfl_xor(v, 1);
        v += __shfl_xor(v, 2);
        v += __shfl_xor(v, 4);
        v += __shfl_xor(v, 8);
        if (threadIdx.x == 0) out[0] = -v / (float)Nn;
    }
}

extern "C" void kernel_launch(void* const* d_in, const int* in_sizes, int n_in,
                              void* d_out, int out_size, void* d_ws, size_t ws_size,
                              hipStream_t stream) {
    const float* za = (const float*)d_in[0];
    const float* zb = (const float*)d_in[1];

    // workspace layout: z_bf16 (4 MB) | rowsum (64 KB) | pospair (32 KB used)
    ushort* z = (ushort*)d_ws;
    float* rowsum = (float*)((char*)d_ws + (size_t)Nn * Dd * 2);
    float* pospair = rowsum + Nn;
    float* out = (float*)d_out;

    convert_kernel<<<2048, 256, 0, stream>>>((const float4*)za, (const float4*)zb, z, rowsum);
    main_kernel<<<N_BLOCKS, 256, 0, stream>>>(z, rowsum, pospair);
    finalize_kernel<<<1, 1024, 0, stream>>>(rowsum, pospair, out);
}

// Round 3
// 177.216 us; speedup vs baseline: 1.2386x; 1.2386x over previous
//
#include <hip/hip_runtime.h>
#include <hip/hip_bf16.h>

// Problem constants (B=8192, D=128 from reference setup_inputs)
constexpr int Bh = 8192;
constexpr int Nn = 16384;   // 2*B
constexpr int Dd = 128;
constexpr float EPS = 1e-8f;
constexpr float LN2 = 0.69314718056f;

constexpr int K_TILES = 8;          // tiles per block
constexpr int N_TILES = 8256;       // 128x128 upper-tri tiles (incl diag): 128*129/2
constexpr int N_BLOCKS = N_TILES / K_TILES;   // 1032, exact

typedef short bf16x8 __attribute__((ext_vector_type(8)));
typedef float f32x4 __attribute__((ext_vector_type(4)));

// ---- Kernel 1: fp32 -> bf16, scaled by sqrt(2*log2e) so MFMA dot == sim/tau*log2e ----
__global__ __launch_bounds__(256) void convert_kernel(const float4* __restrict__ za,
                                                      const float4* __restrict__ zb,
                                                      ushort* __restrict__ z,
                                                      float* __restrict__ rowsum,
                                                      float* __restrict__ out) {
    const int t = blockIdx.x * 256 + threadIdx.x;        // 0 .. 524287
    constexpr int Q = (Bh * Dd) / 4;                     // 262144 float4 per input
    const float SCL = 1.69864363f;                       // sqrt(2 * 1.4426950409)
    float4 v = (t < Q) ? za[t] : zb[t - Q];
    union { ushort4 u4; __hip_bfloat16 h[4]; } cv;
    cv.h[0] = __float2bfloat16(v.x * SCL);
    cv.h[1] = __float2bfloat16(v.y * SCL);
    cv.h[2] = __float2bfloat16(v.z * SCL);
    cv.h[3] = __float2bfloat16(v.w * SCL);
    ((ushort4*)z)[t] = cv.u4;
    if (t < Nn) rowsum[t] = 0.f;
    if (t == 0) out[0] = 0.f;          // finalize accumulates via atomics
}

// tile index g -> row tile t (128-row granularity): largest t with cum(t)=t*(257-t)/2 <= g
__device__ __forceinline__ int row_tile_of(int g) {
    int t = (int)((257.0f - sqrtf(66049.0f - 8.0f * (float)g)) * 0.5f);
    t = t < 0 ? 0 : (t > 127 ? 127 : t);
    while (t * (257 - t) / 2 > g) --t;
    while ((t + 1) * (256 - t) / 2 <= g) ++t;
    return t;
}

// row-credit flush: reduce rs over the 16 col-lanes, one atomic per row (log2 domain)
__device__ __forceinline__ void flush_rs(float* __restrict__ rowsum, int rowW,
                                         float (&rs)[2][4], int q, int c) {
#pragma unroll
    for (int s = 0; s < 2; ++s)
#pragma unroll
        for (int r = 0; r < 4; ++r) {
            float v = rs[s][r];
            v += __shfl_xor(v, 1);
            v += __shfl_xor(v, 2);
            v += __shfl_xor(v, 4);
            v += __shfl_xor(v, 8);
            if (c == 0) atomicAdd(&rowsum[rowW + s * 16 + q * 4 + r], v);
            rs[s][r] = 0.f;
        }
}

// col-credit flush (deferred one tile so the barrier's vmcnt(0) drain never
// waits on fresh HBM-bouncing atomics): reduce over q, one atomic per col
__device__ __forceinline__ void colflush(float* __restrict__ rowsum,
                                         float (&csumP)[8], int C0P, int lane, int c) {
#pragma unroll
    for (int st = 0; st < 8; ++st) {
        float v = csumP[st];
        v += __shfl_xor(v, 16);
        v += __shfl_xor(v, 32);
        if (lane < 16) atomicAdd(&rowsum[C0P + st * 16 + c], v);
    }
}

// Stage one 128x128 bf16 B-tile (32 KB) into LDS via global_load_lds width-16.
// LDS layout is XOR-swizzled: phys (r, b) holds logical (r, b ^ ((r&15)<<4)).
// global_load_lds writes linearly (wave base + lane*16), so the swizzle is
// applied by permuting the GLOBAL source address per lane (m173 pattern).
// Result: ds_read_b128 fragment reads are bank-conflict-free (8 groups x 8 lanes,
// 8 words/bank — same distribution as linear contiguous b128).
__device__ __forceinline__ void stage_tile(const ushort* __restrict__ z, ushort* lbuf,
                                           int C0, int wave, int lane) {
#pragma unroll
    for (int i = 0; i < 8; ++i) {
        const int chunk = wave * 8 + i;              // 32 chunks of 1 KB
        const int r = (chunk << 2) + (lane >> 4);    // row 0..127 (one col of z)
        const int bl = ((lane & 15) ^ (r & 15)) << 4;  // swizzled byte-in-row
        const char* gp = (const char*)z + (((size_t)(C0 + r)) << 8) + bl;
        ushort* lp = lbuf + (chunk << 9);            // wave-uniform LDS base
        __builtin_amdgcn_global_load_lds((const __attribute__((address_space(1))) void*)gp,
                                         (__attribute__((address_space(3))) void*)lp,
                                         16, 0, 0);
    }
}

// ---- Kernel 2: symmetric upper-triangle at 128x128 granularity.
// R2 restructure: B-tile staged to LDS (shared by 4 waves, 4x less global
// traffic), double-buffered, stage issued BEFORE compute so the single
// per-tile __syncthreads() drain (vmcnt(0)+lgkmcnt(0)) finds all VMEM ops
// ~2500 issue-cycles old -> no stall. Col-credit atomics deferred one tile
// for the same reason (atomics write through to HBM: WRITE_SIZE == 4B*atomic
// count in R0/R1, and vmcnt is FIFO so fresh atomics poison counted waits).
// A stays register-resident per wave (32 rows, reloaded on row-panel change).
__global__ __launch_bounds__(256) void main_kernel(const ushort* __restrict__ z,
                                                   float* __restrict__ rowsum,
                                                   float* __restrict__ pospair) {
    __shared__ ushort ldsb[2][16384];     // 2 x 32 KB B-tile double buffer

    const int tid = threadIdx.x;
    const int wave = tid >> 6;
    const int lane = tid & 63;
    const int q = lane >> 4;        // quad: 0..3
    const int c = lane & 15;        // 0..15
    const int g0 = blockIdx.x * K_TILES;

    int tr = row_tile_of(g0);
    int ct = tr + (g0 - tr * (257 - tr) / 2);

    // per-lane swizzled LDS fragment offsets: logical byte (q+4kt)*16 in row c
    int O[4];
#pragma unroll
    for (int kt = 0; kt < 4; ++kt) O[kt] = (c << 8) + ((((q + 4 * kt) ^ c)) << 4);

    bf16x8 afrag[2][4];
    float rs[2][4];
#pragma unroll
    for (int s = 0; s < 2; ++s)
#pragma unroll
        for (int r = 0; r < 4; ++r) rs[s][r] = 0.f;

    float csumP[8];
    int C0P = 0;
    bool pendP = false;
    int cur_tr = -1, rowW = 0, cur = 0;

    stage_tile(z, &ldsb[0][0], ct << 7, wave, lane);
    __syncthreads();

    for (int j = 0; j < K_TILES; ++j) {
        const int C0 = ct << 7;
        const bool diag = (ct == tr);

        if (tr != cur_tr) {                 // row-panel change: flush + reload A
            if (cur_tr >= 0) flush_rs(rowsum, rowW, rs, q, c);
            cur_tr = tr;
            rowW = (tr << 7) + wave * 32;   // this wave's 32-row base
#pragma unroll
            for (int s = 0; s < 2; ++s) {
                const ushort* ap = z + (size_t)(rowW + s * 16 + c) * Dd;
#pragma unroll
                for (int kt = 0; kt < 4; ++kt)
                    afrag[s][kt] = *(const bf16x8*)(ap + kt * 32 + q * 8);
            }
        }

        // deferred col-credit flush from previous tile (atomics get a full
        // tile of compute before the next barrier drains them)
        if (pendP) { colflush(rowsum, csumP, C0P, lane, c); pendP = false; }

        // next tile coords + prefetch-stage into the other buffer
        int trN = tr, ctN = ct + 1;
        if (ctN == 128) { trN = tr + 1; ctN = trN; }
        if (j + 1 < K_TILES) stage_tile(z, &ldsb[cur ^ 1][0], ctN << 7, wave, lane);

        const char* lb = (const char*)&ldsb[cur][0];
        float csum[8];
#pragma unroll
        for (int st = 0; st < 8; ++st) csum[st] = 0.f;

#pragma unroll
        for (int st = 0; st < 8; ++st) {
            bf16x8 bcur[4];
#pragma unroll
            for (int kt = 0; kt < 4; ++kt)
                bcur[kt] = *(const bf16x8*)(lb + O[kt] + st * 4096);

            f32x4 acc[2] = {{0.f,0.f,0.f,0.f},{0.f,0.f,0.f,0.f}};
#pragma unroll
            for (int kt = 0; kt < 4; ++kt) {
#pragma unroll
                for (int s = 0; s < 2; ++s)
                    acc[s] = __builtin_amdgcn_mfma_f32_16x16x32_bf16(afrag[s][kt], bcur[kt], acc[s], 0, 0, 0);
            }
            const int gc0 = C0 + st * 16;
#pragma unroll
            for (int s = 0; s < 2; ++s) {
                const int R = rowW + s * 16;
                float sp[4];
#pragma unroll
                for (int r = 0; r < 4; ++r) {
                    float u = acc[s][r];
                    // softplus in log2 domain: max(u,0) + log2(1 + 2^-|u|)
                    float e = __builtin_amdgcn_exp2f(-fabsf(u));
                    sp[r] = fmaxf(u, 0.f) + __builtin_amdgcn_logf(1.f + e);
                }
                if (diag && gc0 == R) {               // zero self-similarity
#pragma unroll
                    for (int r = 0; r < 4; ++r)
                        if (c == q * 4 + r) sp[r] = 0.f;
                }
                if (gc0 == (R ^ Bh)) {                // positive-pair subtile (rows<8192)
#pragma unroll
                    for (int r = 0; r < 4; ++r)
                        if (c == q * 4 + r) pospair[R + q * 4 + r] = sp[r];
                }
#pragma unroll
                for (int r = 0; r < 4; ++r) rs[s][r] += sp[r];
                if (!diag) csum[st] += (sp[0] + sp[1]) + (sp[2] + sp[3]);
            }
        }

        if (!diag) {    // defer the col-credit atomics past the barrier
#pragma unroll
            for (int st = 0; st < 8; ++st) csumP[st] = csum[st];
            C0P = C0;
            pendP = true;
        }

        __syncthreads();        // drains vmcnt(0): stage + atomics all old
        cur ^= 1;
        tr = trN;
        ct = ctN;
    }

    if (pendP) colflush(rowsum, csumP, C0P, lane, c);
    if (cur_tr >= 0) flush_rs(rowsum, rowW, rs, q, c);
}

// ---- Kernel 3: final loss (log2-domain sums back via ln2), 16 blocks x 1024 ----
__global__ __launch_bounds__(1024) void finalize_kernel(const float* __restrict__ rowsum,
                                                        const float* __restrict__ pospair,
                                                        float* __restrict__ out) {
    __shared__ float red[16];
    const int i = blockIdx.x * 1024 + threadIdx.x;   // 16*1024 == Nn exactly
    float denom = fmaxf(LN2 * rowsum[i], EPS);
    float sp = fmaxf(LN2 * pospair[i & (Bh - 1)], EPS);   // pospair[i]==pospair[i^B]
    float acc = __logf(sp) - __logf(denom);
#pragma unroll
    for (int m = 1; m < 64; m <<= 1) acc += __shfl_xor(acc, m);
    if ((threadIdx.x & 63) == 0) red[threadIdx.x >> 6] = acc;
    __syncthreads();
    if (threadIdx.x < 16) {
        float v = red[threadIdx.x];
        v += __shfl_xor(v, 1);
        v += __shfl_xor(v, 2);
        v += __shfl_xor(v, 4);
        v += __shfl_xor(v, 8);
        if (threadIdx.x == 0) atomicAdd(out, -v / (float)Nn);
    }
}

extern "C" void kernel_launch(void* const* d_in, const int* in_sizes, int n_in,
                              void* d_out, int out_size, void* d_ws, size_t ws_size,
                              hipStream_t stream) {
    const float* za = (const float*)d_in[0];
    const float* zb = (const float*)d_in[1];

    // workspace layout: z_bf16 (4 MB) | rowsum (64 KB) | pospair (32 KB used)
    ushort* z = (ushort*)d_ws;
    float* rowsum = (float*)((char*)d_ws + (size_t)Nn * Dd * 2);
    float* pospair = rowsum + Nn;
    float* out = (float*)d_out;

    convert_kernel<<<2048, 256, 0, stream>>>((const float4*)za, (const float4*)zb, z, rowsum, out);
    main_kernel<<<N_BLOCKS, 256, 0, stream>>>(z, rowsum, pospair);
    finalize_kernel<<<16, 1024, 0, stream>>>(rowsum, pospair, out);
}